// Round 2
// baseline (1188.046 us; speedup 1.0000x reference)
//
#include <hip/hip_runtime.h>
#include <math.h>

// Problem constants (from reference setup_inputs)
#define B_   16
#define C_   64
#define OC_  64
#define H_   128
#define W_   128
#define E_   4
#define K_   3
#define HID_ 16
#define HW_  (H_ * W_)          // 16384
#define TEMP_ 30.0f

// ---------------------------------------------------------------------------
// Kernel 1: global average pool.  One block per (b, c); 16384 floats -> 1.
// ---------------------------------------------------------------------------
__global__ void pool_kernel(const float* __restrict__ x, float* __restrict__ pooled) {
    int bc = blockIdx.x;                         // 0 .. B_*C_-1
    const float4* xp = (const float4*)(x + (size_t)bc * HW_);
    float s = 0.f;
    for (int i = threadIdx.x; i < HW_ / 4; i += 256) {
        float4 v = xp[i];
        s += v.x + v.y + v.z + v.w;
    }
    for (int off = 32; off; off >>= 1) s += __shfl_down(s, off, 64);
    __shared__ float red[4];
    int lane = threadIdx.x & 63, wv = threadIdx.x >> 6;
    if (lane == 0) red[wv] = s;
    __syncthreads();
    if (threadIdx.x == 0) {
        float t = red[0] + red[1] + red[2] + red[3];
        pooled[bc] = t * (1.0f / (float)HW_);
    }
}

// ---------------------------------------------------------------------------
// Kernel 2: control MLP + softmax over experts + mixed biases for 3 layers.
// grid = B_, block = 64 (one thread per oc).
// coeff layout: [b][oc][e]; ab_all layout: [layer][b][oc]
// ---------------------------------------------------------------------------
__global__ void control_kernel(const float* __restrict__ pooled,
                               const float* __restrict__ cw1,   // (HID_, C_)
                               const float* __restrict__ cw2,   // (E_*OC_, HID_)
                               const float* __restrict__ b1,    // (E_, OC_)
                               const float* __restrict__ b2,
                               const float* __restrict__ b3,
                               float* __restrict__ coeff,
                               float* __restrict__ ab_all) {    // 3 * B_ * OC_
    int b = blockIdx.x;
    int t = threadIdx.x;                // 0..63 = oc
    __shared__ float pl[C_];
    __shared__ float hid[HID_];
    pl[t] = pooled[b * C_ + t];
    __syncthreads();
    if (t < HID_) {
        float a = 0.f;
        for (int c = 0; c < C_; ++c) a = fmaf(pl[c], cw1[t * C_ + c], a);
        hid[t] = fmaxf(a, 0.f);
    }
    __syncthreads();
    float l[E_];
#pragma unroll
    for (int e = 0; e < E_; ++e) {
        float a = 0.f;
#pragma unroll
        for (int h = 0; h < HID_; ++h) a = fmaf(hid[h], cw2[(t * E_ + e) * HID_ + h], a);
        l[e] = a * (1.0f / TEMP_);
    }
    float m = fmaxf(fmaxf(l[0], l[1]), fmaxf(l[2], l[3]));
    float p[E_], s = 0.f;
#pragma unroll
    for (int e = 0; e < E_; ++e) { p[e] = expf(l[e] - m); s += p[e]; }
    float inv = 1.0f / s;
#pragma unroll
    for (int e = 0; e < E_; ++e) p[e] *= inv;
#pragma unroll
    for (int e = 0; e < E_; ++e) coeff[(b * OC_ + t) * E_ + e] = p[e];
    // mixed biases (einsum 'boe,eo->bo') for all three layers
    float a1 = 0.f, a2 = 0.f, a3 = 0.f;
#pragma unroll
    for (int e = 0; e < E_; ++e) {
        a1 = fmaf(p[e], b1[e * OC_ + t], a1);
        a2 = fmaf(p[e], b2[e * OC_ + t], a2);
        a3 = fmaf(p[e], b3[e * OC_ + t], a3);
    }
    ab_all[0 * B_ * OC_ + b * OC_ + t] = a1;
    ab_all[1 * B_ * OC_ + b * OC_ + t] = a2;
    ab_all[2 * B_ * OC_ + b * OC_ + t] = a3;
}

// ---------------------------------------------------------------------------
// Kernel 3: mix expert conv weights for all 3 layers (blockIdx.y = layer).
// agg[b,oc,c,k,l] = sum_e coeff[b,oc,e] * w[e,oc,c,k,l], float4 over 576 tail.
// ---------------------------------------------------------------------------
__global__ void aggw_kernel(const float* __restrict__ coeff,
                            const float* __restrict__ w1,
                            const float* __restrict__ w2,
                            const float* __restrict__ w3,
                            float* __restrict__ o1,
                            float* __restrict__ o2,
                            float* __restrict__ o3) {
    const int NJ = (C_ * 9) / 4;                 // 144 float4 per (b,oc)
    int i = blockIdx.x * blockDim.x + threadIdx.x;
    if (i >= B_ * OC_ * NJ) return;
    const float* w  = (blockIdx.y == 0) ? w1 : (blockIdx.y == 1) ? w2 : w3;
    float*       out = (blockIdx.y == 0) ? o1 : (blockIdx.y == 1) ? o2 : o3;
    int bo = i / NJ;
    int j  = i - bo * NJ;
    int oc = bo & (OC_ - 1);
    float c0 = coeff[bo * E_ + 0], c1 = coeff[bo * E_ + 1];
    float c2 = coeff[bo * E_ + 2], c3 = coeff[bo * E_ + 3];
    const float4* wp = (const float4*)w;
    const int se = OC_ * NJ;                     // expert stride in float4
    float4 w0 = wp[oc * NJ + j];
    float4 wA = wp[se + oc * NJ + j];
    float4 wB = wp[2 * se + oc * NJ + j];
    float4 wC = wp[3 * se + oc * NJ + j];
    float4 r;
    r.x = c0 * w0.x + c1 * wA.x + c2 * wB.x + c3 * wC.x;
    r.y = c0 * w0.y + c1 * wA.y + c2 * wB.y + c3 * wC.y;
    r.z = c0 * w0.z + c1 * wA.z + c2 * wB.z + c3 * wC.z;
    r.w = c0 * w0.w + c1 * wA.w + c2 * wB.w + c3 * wC.w;
    ((float4*)out)[i] = r;
}

// ---------------------------------------------------------------------------
// Kernel 4: direct 3x3 conv, pad=1, stride=1, Cin=OC=64, per-sample weights.
// Block: 256 threads = (tx:4)x(ty:16)x(og:4).  Block tile: 16 oc, 16 h, 32 w.
// Each thread: 8 consecutive x pixels * 4 oc.
// Channel-chunked LDS staging (CC channels / chunk).
// s_in rows padded to 36 floats -> 16B-aligned rows, x0=tx*8 -> 32B-aligned
// so row reads vectorize to b128+b128+b64.  s_w rows padded to 12 floats.
// ---------------------------------------------------------------------------
#define CC 16
__launch_bounds__(256, 2)
__global__ void conv3x3_kernel(const float* __restrict__ in,    // (B_,64,H_,W_)
                               const float* __restrict__ wagg,  // (B_,64,64,9)
                               const float* __restrict__ bagg,  // (B_,64)
                               float* __restrict__ out) {       // (B_,64,H_,W_)
    const int bx  = blockIdx.x * 32;
    const int by  = blockIdx.y * 16;
    const int b   = blockIdx.z >> 2;
    const int ocb = (blockIdx.z & 3) * 16;

    const int t  = threadIdx.x;
    const int tx = t & 3;
    const int ty = (t >> 2) & 15;
    const int og = t >> 6;               // wave-uniform
    const int x0 = tx * 8;

    __shared__ __align__(16) float s_in[CC][18][36];
    __shared__ __align__(16) float s_w[CC][16][12];

    float acc[4][8];
#pragma unroll
    for (int o = 0; o < 4; ++o)
#pragma unroll
        for (int p = 0; p < 8; ++p) acc[o][p] = 0.f;

    const size_t in_b = (size_t)b * C_ * HW_;

    for (int cb = 0; cb < C_; cb += CC) {
        __syncthreads();
        // ---- stage input tile (CC x 18 x 34 logical) ----
        for (int idx = t; idx < CC * 18 * 34; idx += 256) {
            int c   = idx / (18 * 34);
            int rem = idx - c * (18 * 34);
            int row = rem / 34;
            int col = rem - row * 34;
            int h = by + row - 1;
            int w = bx + col - 1;
            float v = 0.f;
            if ((unsigned)h < H_ && (unsigned)w < W_)
                v = in[in_b + (size_t)(cb + c) * HW_ + h * W_ + w];
            s_in[c][row][col] = v;
        }
        // ---- stage weights: 16 oc x CC c x 9 (rows padded to 12) ----
        for (int idx = t; idx < 16 * CC * 9; idx += 256) {
            int c   = idx / 144;
            int rem = idx - c * 144;
            int o   = rem / 9;
            int k   = rem - o * 9;
            s_w[c][o][k] = wagg[((size_t)b * OC_ + ocb + o) * (C_ * 9) + (cb + c) * 9 + k];
        }
        __syncthreads();

        for (int c = 0; c < CC; ++c) {
            float r[3][10];
#pragma unroll
            for (int dy = 0; dy < 3; ++dy) {
                const float4* rp = (const float4*)&s_in[c][ty + dy][x0];
                float4 va = rp[0];
                float4 vb = rp[1];
                float2 vc = *(const float2*)&s_in[c][ty + dy][x0 + 8];
                r[dy][0] = va.x; r[dy][1] = va.y; r[dy][2] = va.z; r[dy][3] = va.w;
                r[dy][4] = vb.x; r[dy][5] = vb.y; r[dy][6] = vb.z; r[dy][7] = vb.w;
                r[dy][8] = vc.x; r[dy][9] = vc.y;
            }
#pragma unroll
            for (int o = 0; o < 4; ++o) {
                const float4* wp4 = (const float4*)&s_w[c][og * 4 + o][0];
                float4 wa = wp4[0];
                float4 wb = wp4[1];
                float wv[9];
                wv[0] = wa.x; wv[1] = wa.y; wv[2] = wa.z; wv[3] = wa.w;
                wv[4] = wb.x; wv[5] = wb.y; wv[6] = wb.z; wv[7] = wb.w;
                wv[8] = s_w[c][og * 4 + o][8];
#pragma unroll
                for (int dy = 0; dy < 3; ++dy)
#pragma unroll
                    for (int dx = 0; dx < 3; ++dx)
#pragma unroll
                        for (int p = 0; p < 8; ++p)
                            acc[o][p] = fmaf(r[dy][p + dx], wv[dy * 3 + dx], acc[o][p]);
            }
        }
    }

    // ---- epilogue: bias + store (32B-aligned float4 pairs) ----
    const size_t out_b = (size_t)b * OC_ * HW_;
#pragma unroll
    for (int o = 0; o < 4; ++o) {
        int oc = ocb + og * 4 + o;
        float bias = bagg[b * OC_ + oc];
        float* op = out + out_b + (size_t)oc * HW_ + (by + ty) * W_ + bx + x0;
        float4 v0 = { acc[o][0] + bias, acc[o][1] + bias, acc[o][2] + bias, acc[o][3] + bias };
        float4 v1 = { acc[o][4] + bias, acc[o][5] + bias, acc[o][6] + bias, acc[o][7] + bias };
        ((float4*)op)[0] = v0;
        ((float4*)op)[1] = v1;
    }
}

// ---------------------------------------------------------------------------
// Launch
// ---------------------------------------------------------------------------
extern "C" void kernel_launch(void* const* d_in, const int* in_sizes, int n_in,
                              void* d_out, int out_size, void* d_ws, size_t ws_size,
                              hipStream_t stream) {
    const float* x   = (const float*)d_in[0];
    const float* cw1 = (const float*)d_in[1];
    const float* cw2 = (const float*)d_in[2];
    const float* w1  = (const float*)d_in[3];
    const float* w2  = (const float*)d_in[4];
    const float* w3  = (const float*)d_in[5];
    const float* b1  = (const float*)d_in[6];
    const float* b2  = (const float*)d_in[7];
    const float* b3  = (const float*)d_in[8];

    float* ws = (float*)d_ws;
    // workspace layout (floats); all offsets 16B aligned
    float* pooled = ws;                       // 1024
    float* coeff  = ws + 1024;                // 4096
    float* ab_all = ws + 5120;                // 3*1024 = 3072
    float* aw1    = ws + 8192;                // 589824 each
    float* aw2    = aw1 + 589824;
    float* aw3    = aw2 + 589824;
    float* buf1   = aw3 + 589824;             // 16777216 each
    float* buf2   = buf1 + 16777216;
    // total ~= 35.3M floats ~= 141.3 MB

    pool_kernel<<<B_ * C_, 256, 0, stream>>>(x, pooled);
    control_kernel<<<B_, 64, 0, stream>>>(pooled, cw1, cw2, b1, b2, b3,
                                          coeff, ab_all);
    {
        dim3 g(576, 3);
        aggw_kernel<<<g, 256, 0, stream>>>(coeff, w1, w2, w3, aw1, aw2, aw3);
    }
    float* ab1 = ab_all;
    float* ab2 = ab_all + B_ * OC_;
    float* ab3 = ab_all + 2 * B_ * OC_;

    dim3 grid(W_ / 32, H_ / 16, B_ * 4);
    conv3x3_kernel<<<grid, 256, 0, stream>>>(x,    aw1, ab1, buf1);
    conv3x3_kernel<<<grid, 256, 0, stream>>>(buf1, aw2, ab2, buf2);
    conv3x3_kernel<<<grid, 256, 0, stream>>>(buf2, aw3, ab3, (float*)d_out);
}

// Round 4
// 742.250 us; speedup vs baseline: 1.6006x; 1.6006x over previous
//
#include <hip/hip_runtime.h>
#include <math.h>

// Problem constants
#define B_   16
#define C_   64
#define OC_  64
#define H_   128
#define W_   128
#define E_   4
#define HID_ 16
#define HW_  (H_ * W_)          // 16384
#define TEMP_ 30.0f

typedef float f32x4 __attribute__((ext_vector_type(4)));
typedef short s16x8 __attribute__((ext_vector_type(8)));
typedef short s16x4 __attribute__((ext_vector_type(4)));

__device__ __forceinline__ unsigned short f2bf(float f) {
    unsigned u = __float_as_uint(f);
    u = u + 0x7FFFu + ((u >> 16) & 1u);          // round-to-nearest-even
    return (unsigned short)(u >> 16);
}
__device__ __forceinline__ float bf2f(unsigned short h) {
    return __uint_as_float(((unsigned)h) << 16);
}

// ---------------------------------------------------------------------------
// K1: global average pool. One block per (b,c).
// ---------------------------------------------------------------------------
__global__ void pool_kernel(const float* __restrict__ x, float* __restrict__ pooled) {
    int bc = blockIdx.x;
    const float4* xp = (const float4*)(x + (size_t)bc * HW_);
    float s = 0.f;
    for (int i = threadIdx.x; i < HW_ / 4; i += 256) {
        float4 v = xp[i];
        s += v.x + v.y + v.z + v.w;
    }
    for (int off = 32; off; off >>= 1) s += __shfl_down(s, off, 64);
    __shared__ float red[4];
    int lane = threadIdx.x & 63, wv = threadIdx.x >> 6;
    if (lane == 0) red[wv] = s;
    __syncthreads();
    if (threadIdx.x == 0)
        pooled[bc] = (red[0] + red[1] + red[2] + red[3]) * (1.0f / (float)HW_);
}

// ---------------------------------------------------------------------------
// K2: control MLP + softmax + mixed biases (3 layers). grid=B_, block=64.
// ---------------------------------------------------------------------------
__global__ void control_kernel(const float* __restrict__ pooled,
                               const float* __restrict__ cw1,
                               const float* __restrict__ cw2,
                               const float* __restrict__ b1,
                               const float* __restrict__ b2,
                               const float* __restrict__ b3,
                               float* __restrict__ coeff,
                               float* __restrict__ ab_all) {
    int b = blockIdx.x;
    int t = threadIdx.x;                // oc
    __shared__ float pl[C_];
    __shared__ float hid[HID_];
    pl[t] = pooled[b * C_ + t];
    __syncthreads();
    if (t < HID_) {
        float a = 0.f;
        for (int c = 0; c < C_; ++c) a = fmaf(pl[c], cw1[t * C_ + c], a);
        hid[t] = fmaxf(a, 0.f);
    }
    __syncthreads();
    float l[E_];
#pragma unroll
    for (int e = 0; e < E_; ++e) {
        float a = 0.f;
#pragma unroll
        for (int h = 0; h < HID_; ++h) a = fmaf(hid[h], cw2[(t * E_ + e) * HID_ + h], a);
        l[e] = a * (1.0f / TEMP_);
    }
    float m = fmaxf(fmaxf(l[0], l[1]), fmaxf(l[2], l[3]));
    float p[E_], s = 0.f;
#pragma unroll
    for (int e = 0; e < E_; ++e) { p[e] = expf(l[e] - m); s += p[e]; }
    float inv = 1.0f / s;
#pragma unroll
    for (int e = 0; e < E_; ++e) { p[e] *= inv; coeff[(b * OC_ + t) * E_ + e] = p[e]; }
    float a1 = 0.f, a2 = 0.f, a3 = 0.f;
#pragma unroll
    for (int e = 0; e < E_; ++e) {
        a1 = fmaf(p[e], b1[e * OC_ + t], a1);
        a2 = fmaf(p[e], b2[e * OC_ + t], a2);
        a3 = fmaf(p[e], b3[e * OC_ + t], a3);
    }
    ab_all[0 * B_ * OC_ + b * OC_ + t] = a1;
    ab_all[1 * B_ * OC_ + b * OC_ + t] = a2;
    ab_all[2 * B_ * OC_ + b * OC_ + t] = a3;
}

// ---------------------------------------------------------------------------
// K3: mix expert weights, split to bf16 hi/lo, reorder to [b][oc][tap][c].
// idx = ((b*64+oc)*9+tap)*64+c ; grid.y = layer. 2304x256 = 589824 exact.
// src w layout: (E, OC, C, 3, 3) -> ((e*64+oc)*64+c)*9+tap
// ---------------------------------------------------------------------------
__global__ void aggw_split(const float* __restrict__ coeff,
                           const float* __restrict__ w1,
                           const float* __restrict__ w2,
                           const float* __restrict__ w3,
                           unsigned short* __restrict__ Wh1, unsigned short* __restrict__ Wl1,
                           unsigned short* __restrict__ Wh2, unsigned short* __restrict__ Wl2,
                           unsigned short* __restrict__ Wh3, unsigned short* __restrict__ Wl3) {
    int layer = blockIdx.y;
    const float* w = (layer == 0) ? w1 : (layer == 1) ? w2 : w3;
    unsigned short* Wh = (layer == 0) ? Wh1 : (layer == 1) ? Wh2 : Wh3;
    unsigned short* Wl = (layer == 0) ? Wl1 : (layer == 1) ? Wl2 : Wl3;

    int idx = blockIdx.x * 256 + threadIdx.x;     // < 589824
    int c   = idx & 63;
    int r   = idx >> 6;                           // < 9216
    int tap = r % 9;
    int r2  = r / 9;                              // < 1024
    int oc  = r2 & 63;
    int b   = r2 >> 6;

    float s = 0.f;
#pragma unroll
    for (int e = 0; e < E_; ++e)
        s = fmaf(coeff[(b * OC_ + oc) * E_ + e],
                 w[(((size_t)e * OC_ + oc) * C_ + c) * 9 + tap], s);
    unsigned short h = f2bf(s);
    Wh[idx] = h;
    Wl[idx] = f2bf(s - bf2f(h));
}

// ---------------------------------------------------------------------------
// K4: convert+transpose x: fp32 [b][c][hw] -> bf16 hi/lo [b][hw][c].
// block 256; grid (256 hw-tiles of 64, 16 b). LDS transpose tile 64x64.
// ---------------------------------------------------------------------------
__global__ void xcvt_kernel(const float* __restrict__ x,
                            unsigned short* __restrict__ Xh,
                            unsigned short* __restrict__ Xl) {
    __shared__ float tr[64][65];
    const int b   = blockIdx.y;
    const int hw0 = blockIdx.x * 64;
    const int t   = threadIdx.x;
    const int l   = t & 63;
    const int wv  = t >> 6;
    const float* src = x + (size_t)b * C_ * HW_;
#pragma unroll
    for (int i = 0; i < 16; ++i) {
        int c = wv * 16 + i;
        tr[l][c] = src[(size_t)c * HW_ + hw0 + l];
    }
    __syncthreads();
#pragma unroll
    for (int i = 0; i < 2; ++i) {
        int g  = t + i * 256;                 // < 512
        int px = g >> 3;
        int cg = (g & 7) << 3;
        s16x8 hv, lv;
#pragma unroll
        for (int j = 0; j < 8; ++j) {
            float v = tr[px][cg + j];
            unsigned short h = f2bf(v);
            hv[j] = (short)h;
            lv[j] = (short)f2bf(v - bf2f(h));
        }
        size_t dst = ((size_t)b * HW_ + hw0 + px) * 64 + cg;
        *(s16x8*)(Xh + dst) = hv;
        *(s16x8*)(Xl + dst) = lv;
    }
}

// ---------------------------------------------------------------------------
// K5: split-bf16 MFMA conv (3x3, pad 1, per-sample weights).
// Block = 256 thr (4 waves) = one output row py (128 px) x 64 oc of sample b.
// Wave w: px [w*32, w*32+32), all 64 oc -> acc[4 octile][2 ntile] f32x4.
// K loop: 2 chunks of 32 channels; LDS holds X tile [3 rows][130 cols][hi/lo][32c]
// with 16B-slot XOR swizzle: byte = (row*130+col)*128 + ((m*4+q)^(col&7))*16.
// D = Wh*Xh + Wh*Xl + Wl*Xh  (fp32 acc; dropped Wl*Xl ~2^-18).
// ---------------------------------------------------------------------------
__launch_bounds__(256, 2)
__global__ void conv_mfma(const unsigned short* __restrict__ Xh,
                          const unsigned short* __restrict__ Xl,
                          const unsigned short* __restrict__ Wh,
                          const unsigned short* __restrict__ Wl,
                          const float* __restrict__ bias,     // [B][64]
                          unsigned short* __restrict__ Yh,    // next-stage hi (if !final)
                          unsigned short* __restrict__ Yl,    // next-stage lo
                          float* __restrict__ Yf,             // final fp32 NCHW
                          int final_layer) {
    const int py = blockIdx.x;      // 0..127
    const int b  = blockIdx.y;      // 0..15
    const int t  = threadIdx.x;
    const int l  = t & 63;
    const int wv = t >> 6;
    const int lq = l >> 4;          // lane quarter (k-subchunk)
    const int ln = l & 15;

    __shared__ __align__(16) unsigned short lds[3 * 130 * 64];  // 49920 B

    f32x4 acc[4][2];
#pragma unroll
    for (int o = 0; o < 4; ++o)
#pragma unroll
        for (int n = 0; n < 2; ++n)
#pragma unroll
            for (int r = 0; r < 4; ++r) acc[o][n][r] = 0.f;

    const size_t xbase = (size_t)b * HW_ * 64;    // channel-last activation base
    const size_t wbase = (size_t)b * OC_ * 9 * 64;

    for (int chunk = 0; chunk < 2; ++chunk) {
        const int cbase = chunk * 32;
        __syncthreads();
        // ---- stage X tile: 3120 granules of 16B (8 channels) ----
        for (int i = 0; i < 13; ++i) {
            int idx = t + i * 256;
            if (idx < 3120) {
                int q    = idx & 3;
                int m    = (idx >> 2) & 1;
                int rest = idx >> 3;              // < 390
                int row  = rest / 130;
                int col  = rest - row * 130;
                int ir   = py + row - 1;
                int ic   = col - 1;
                s16x8 v;
#pragma unroll
                for (int j = 0; j < 8; ++j) v[j] = 0;
                if ((unsigned)ir < (unsigned)H_ && (unsigned)ic < (unsigned)W_) {
                    const unsigned short* src = (m ? Xl : Xh) + xbase
                        + ((size_t)(ir * W_ + ic)) * 64 + cbase + q * 8;
                    v = *(const s16x8*)src;
                }
                int slot = ((m << 2) | q) ^ (col & 7);
                *(s16x8*)&lds[((row * 130 + col) << 6) + (slot << 3)] = v;
            }
        }
        __syncthreads();

        // ---- compute: 9 taps, A ping-pong prefetch ----
        s16x8 Ah[2][4], Al[2][4];
#define LOADA(tp, pp)                                                          \
        {                                                                      \
            _Pragma("unroll")                                                  \
            for (int oct = 0; oct < 4; ++oct) {                                \
                size_t off = wbase + ((size_t)((oct * 16 + ln) * 9 + (tp))) * 64 \
                             + cbase + lq * 8;                                 \
                Ah[pp][oct] = *(const s16x8*)(Wh + off);                       \
                Al[pp][oct] = *(const s16x8*)(Wl + off);                       \
            }                                                                  \
        }
        LOADA(0, 0);
#pragma unroll
        for (int tap = 0; tap < 9; ++tap) {
            const int pp = tap & 1;
            if (tap < 8) LOADA(tap + 1, pp ^ 1);
            const int ky = tap / 3;
            const int kx = tap % 3;
            s16x8 Bh[2], Bl[2];
#pragma unroll
            for (int nt = 0; nt < 2; ++nt) {
                int col = wv * 32 + nt * 16 + ln + kx;      // 0..129
                unsigned base = (unsigned)((ky * 130 + col) << 6);
                int sh = (lq ^ (col & 7)) << 3;
                int sl = ((4 | lq) ^ (col & 7)) << 3;
                Bh[nt] = *(const s16x8*)&lds[base + sh];
                Bl[nt] = *(const s16x8*)&lds[base + sl];
            }
#pragma unroll
            for (int oct = 0; oct < 4; ++oct)
#pragma unroll
                for (int nt = 0; nt < 2; ++nt)
                    acc[oct][nt] = __builtin_amdgcn_mfma_f32_16x16x32_bf16(
                        Ah[pp][oct], Bh[nt], acc[oct][nt], 0, 0, 0);
#pragma unroll
            for (int oct = 0; oct < 4; ++oct)
#pragma unroll
                for (int nt = 0; nt < 2; ++nt)
                    acc[oct][nt] = __builtin_amdgcn_mfma_f32_16x16x32_bf16(
                        Ah[pp][oct], Bl[nt], acc[oct][nt], 0, 0, 0);
#pragma unroll
            for (int oct = 0; oct < 4; ++oct)
#pragma unroll
                for (int nt = 0; nt < 2; ++nt)
                    acc[oct][nt] = __builtin_amdgcn_mfma_f32_16x16x32_bf16(
                        Al[pp][oct], Bh[nt], acc[oct][nt], 0, 0, 0);
        }
#undef LOADA
    }

    // ---- epilogue: bias + store ----
    // C/D layout (m89): col = l&15 = px-in-tile, row = lq*4 + reg = oc-in-tile.
    float bia[4][4];
#pragma unroll
    for (int oct = 0; oct < 4; ++oct)
#pragma unroll
        for (int r = 0; r < 4; ++r)
            bia[oct][r] = bias[b * OC_ + oct * 16 + lq * 4 + r];

    if (!final_layer) {
#pragma unroll
        for (int oct = 0; oct < 4; ++oct)
#pragma unroll
            for (int nt = 0; nt < 2; ++nt) {
                int px  = wv * 32 + nt * 16 + ln;
                int oc0 = oct * 16 + lq * 4;
                s16x4 hv, lv;
#pragma unroll
                for (int r = 0; r < 4; ++r) {
                    float v = acc[oct][nt][r] + bia[oct][r];
                    unsigned short h = f2bf(v);
                    hv[r] = (short)h;
                    lv[r] = (short)f2bf(v - bf2f(h));
                }
                size_t dst = xbase + ((size_t)(py * W_ + px)) * 64 + oc0;
                *(s16x4*)(Yh + dst) = hv;
                *(s16x4*)(Yl + dst) = lv;
            }
    } else {
#pragma unroll
        for (int oct = 0; oct < 4; ++oct)
#pragma unroll
            for (int nt = 0; nt < 2; ++nt) {
                int px = wv * 32 + nt * 16 + ln;
#pragma unroll
                for (int r = 0; r < 4; ++r) {
                    int oc = oct * 16 + lq * 4 + r;
                    Yf[((size_t)(b * OC_ + oc)) * HW_ + py * W_ + px] =
                        acc[oct][nt][r] + bia[oct][r];
                }
            }
    }
}

// ---------------------------------------------------------------------------
// Launch
// ---------------------------------------------------------------------------
extern "C" void kernel_launch(void* const* d_in, const int* in_sizes, int n_in,
                              void* d_out, int out_size, void* d_ws, size_t ws_size,
                              hipStream_t stream) {
    const float* x   = (const float*)d_in[0];
    const float* cw1 = (const float*)d_in[1];
    const float* cw2 = (const float*)d_in[2];
    const float* w1  = (const float*)d_in[3];
    const float* w2  = (const float*)d_in[4];
    const float* w3  = (const float*)d_in[5];
    const float* b1  = (const float*)d_in[6];
    const float* b2  = (const float*)d_in[7];
    const float* b3  = (const float*)d_in[8];

    char* ws = (char*)d_ws;
    // byte offsets (all 16B aligned)
    float* pooled = (float*)(ws + 0);            //  4 KB
    float* coeff  = (float*)(ws + 4096);         // 16 KB
    float* ab_all = (float*)(ws + 20480);        // 12 KB
    const size_t WSZ = (size_t)B_ * OC_ * 9 * 64 * 2;   // 1,179,648 B per W array
    unsigned short* Wh1 = (unsigned short*)(ws + 32768);
    unsigned short* Wl1 = (unsigned short*)(ws + 32768 + 1 * WSZ);
    unsigned short* Wh2 = (unsigned short*)(ws + 32768 + 2 * WSZ);
    unsigned short* Wl2 = (unsigned short*)(ws + 32768 + 3 * WSZ);
    unsigned short* Wh3 = (unsigned short*)(ws + 32768 + 4 * WSZ);
    unsigned short* Wl3 = (unsigned short*)(ws + 32768 + 5 * WSZ);
    const size_t SOFF = 32768 + 6 * WSZ;                 // 7,110,656
    const size_t SSZ  = (size_t)B_ * HW_ * 64 * 2;       // 33,554,432 B per stage array
    unsigned short* S0h = (unsigned short*)(ws + SOFF);
    unsigned short* S0l = (unsigned short*)(ws + SOFF + 1 * SSZ);
    unsigned short* S1h = (unsigned short*)(ws + SOFF + 2 * SSZ);
    unsigned short* S1l = (unsigned short*)(ws + SOFF + 3 * SSZ);
    // total = 7,110,656 + 4*33,554,432 = 141,328,384 B (same budget as prev round)

    float* ab1 = ab_all;
    float* ab2 = ab_all + B_ * OC_;
    float* ab3 = ab_all + 2 * B_ * OC_;

    pool_kernel<<<B_ * C_, 256, 0, stream>>>(x, pooled);
    control_kernel<<<B_, 64, 0, stream>>>(pooled, cw1, cw2, b1, b2, b3, coeff, ab_all);
    {
        dim3 g(2304, 3);
        aggw_split<<<g, 256, 0, stream>>>(coeff, w1, w2, w3,
                                          Wh1, Wl1, Wh2, Wl2, Wh3, Wl3);
    }
    {
        dim3 g(HW_ / 64, B_);
        xcvt_kernel<<<g, 256, 0, stream>>>(x, S0h, S0l);
    }
    dim3 cg(H_, B_);
    conv_mfma<<<cg, 256, 0, stream>>>(S0h, S0l, Wh1, Wl1, ab1, S1h, S1l, nullptr, 0);
    conv_mfma<<<cg, 256, 0, stream>>>(S1h, S1l, Wh2, Wl2, ab2, S0h, S0l, nullptr, 0);
    conv_mfma<<<cg, 256, 0, stream>>>(S0h, S0l, Wh3, Wl3, ab3, nullptr, nullptr,
                                      (float*)d_out, 1);
}

// Round 5
// 541.676 us; speedup vs baseline: 2.1933x; 1.3703x over previous
//
#include <hip/hip_runtime.h>
#include <math.h>

// Problem constants
#define B_   16
#define C_   64
#define OC_  64
#define H_   128
#define W_   128
#define E_   4
#define HID_ 16
#define HW_  (H_ * W_)          // 16384
#define TEMP_ 30.0f

// Activation plane: [kind(h=0,l=1)][chunk(0,1)][b][hw][32ch], bf16.
// PSTR = shorts per plane.
#define PSTR ((size_t)B_ * HW_ * 32)

typedef float f32x4 __attribute__((ext_vector_type(4)));
typedef short s16x8 __attribute__((ext_vector_type(8)));
typedef short s16x4 __attribute__((ext_vector_type(4)));

__device__ __forceinline__ unsigned short f2bf(float f) {
    unsigned u = __float_as_uint(f);
    u = u + 0x7FFFu + ((u >> 16) & 1u);          // round-to-nearest-even
    return (unsigned short)(u >> 16);
}
__device__ __forceinline__ float bf2f(unsigned short h) {
    return __uint_as_float(((unsigned)h) << 16);
}

// ---------------------------------------------------------------------------
// K1: global average pool. One block per (b,c).
// ---------------------------------------------------------------------------
__global__ void pool_kernel(const float* __restrict__ x, float* __restrict__ pooled) {
    int bc = blockIdx.x;
    const float4* xp = (const float4*)(x + (size_t)bc * HW_);
    float s = 0.f;
    for (int i = threadIdx.x; i < HW_ / 4; i += 256) {
        float4 v = xp[i];
        s += v.x + v.y + v.z + v.w;
    }
    for (int off = 32; off; off >>= 1) s += __shfl_down(s, off, 64);
    __shared__ float red[4];
    int lane = threadIdx.x & 63, wv = threadIdx.x >> 6;
    if (lane == 0) red[wv] = s;
    __syncthreads();
    if (threadIdx.x == 0)
        pooled[bc] = (red[0] + red[1] + red[2] + red[3]) * (1.0f / (float)HW_);
}

// ---------------------------------------------------------------------------
// K2: control MLP + softmax + mixed biases (3 layers). grid=B_, block=64.
// ---------------------------------------------------------------------------
__global__ void control_kernel(const float* __restrict__ pooled,
                               const float* __restrict__ cw1,
                               const float* __restrict__ cw2,
                               const float* __restrict__ b1,
                               const float* __restrict__ b2,
                               const float* __restrict__ b3,
                               float* __restrict__ coeff,
                               float* __restrict__ ab_all) {
    int b = blockIdx.x;
    int t = threadIdx.x;                // oc
    __shared__ float pl[C_];
    __shared__ float hid[HID_];
    pl[t] = pooled[b * C_ + t];
    __syncthreads();
    if (t < HID_) {
        float a = 0.f;
        for (int c = 0; c < C_; ++c) a = fmaf(pl[c], cw1[t * C_ + c], a);
        hid[t] = fmaxf(a, 0.f);
    }
    __syncthreads();
    float l[E_];
#pragma unroll
    for (int e = 0; e < E_; ++e) {
        float a = 0.f;
#pragma unroll
        for (int h = 0; h < HID_; ++h) a = fmaf(hid[h], cw2[(t * E_ + e) * HID_ + h], a);
        l[e] = a * (1.0f / TEMP_);
    }
    float m = fmaxf(fmaxf(l[0], l[1]), fmaxf(l[2], l[3]));
    float p[E_], s = 0.f;
#pragma unroll
    for (int e = 0; e < E_; ++e) { p[e] = expf(l[e] - m); s += p[e]; }
    float inv = 1.0f / s;
#pragma unroll
    for (int e = 0; e < E_; ++e) { p[e] *= inv; coeff[(b * OC_ + t) * E_ + e] = p[e]; }
    float a1 = 0.f, a2 = 0.f, a3 = 0.f;
#pragma unroll
    for (int e = 0; e < E_; ++e) {
        a1 = fmaf(p[e], b1[e * OC_ + t], a1);
        a2 = fmaf(p[e], b2[e * OC_ + t], a2);
        a3 = fmaf(p[e], b3[e * OC_ + t], a3);
    }
    ab_all[0 * B_ * OC_ + b * OC_ + t] = a1;
    ab_all[1 * B_ * OC_ + b * OC_ + t] = a2;
    ab_all[2 * B_ * OC_ + b * OC_ + t] = a3;
}

// ---------------------------------------------------------------------------
// K3: mix expert weights, split to bf16 hi/lo, reorder to [b][oc][tap][64c].
// idx = ((b*64+oc)*9+tap)*64+c ; grid.y = layer. 2304x256 = 589824 exact.
// src w layout: (E, OC, C, 3, 3)
// ---------------------------------------------------------------------------
__global__ void aggw_split(const float* __restrict__ coeff,
                           const float* __restrict__ w1,
                           const float* __restrict__ w2,
                           const float* __restrict__ w3,
                           unsigned short* __restrict__ Wh1, unsigned short* __restrict__ Wl1,
                           unsigned short* __restrict__ Wh2, unsigned short* __restrict__ Wl2,
                           unsigned short* __restrict__ Wh3, unsigned short* __restrict__ Wl3) {
    int layer = blockIdx.y;
    const float* w = (layer == 0) ? w1 : (layer == 1) ? w2 : w3;
    unsigned short* Wh = (layer == 0) ? Wh1 : (layer == 1) ? Wh2 : Wh3;
    unsigned short* Wl = (layer == 0) ? Wl1 : (layer == 1) ? Wl2 : Wl3;

    int idx = blockIdx.x * 256 + threadIdx.x;     // < 589824
    int c   = idx & 63;
    int r   = idx >> 6;                           // < 9216
    int tap = r % 9;
    int r2  = r / 9;                              // < 1024
    int oc  = r2 & 63;
    int b   = r2 >> 6;

    float s = 0.f;
#pragma unroll
    for (int e = 0; e < E_; ++e)
        s = fmaf(coeff[(b * OC_ + oc) * E_ + e],
                 w[(((size_t)e * OC_ + oc) * C_ + c) * 9 + tap], s);
    unsigned short h = f2bf(s);
    Wh[idx] = h;
    Wl[idx] = f2bf(s - bf2f(h));
}

// ---------------------------------------------------------------------------
// K4: convert+transpose x: fp32 [b][c][hw] -> 4 bf16 planes [k][ch-chunk][b][hw][32].
// ---------------------------------------------------------------------------
__global__ void xcvt_kernel(const float* __restrict__ x,
                            unsigned short* __restrict__ Xs) {
    __shared__ float tr[64][65];
    const int b   = blockIdx.y;
    const int hw0 = blockIdx.x * 64;
    const int t   = threadIdx.x;
    const int l   = t & 63;
    const int wv  = t >> 6;
    const float* src = x + (size_t)b * C_ * HW_;
#pragma unroll
    for (int i = 0; i < 16; ++i) {
        int c = wv * 16 + i;
        tr[l][c] = src[(size_t)c * HW_ + hw0 + l];
    }
    __syncthreads();
#pragma unroll
    for (int i = 0; i < 2; ++i) {
        int g  = t + i * 256;                 // < 512
        int px = g >> 3;
        int cg = (g & 7) << 3;                // channel-group base (0..56 by 8)
        s16x8 hv, lv;
#pragma unroll
        for (int j = 0; j < 8; ++j) {
            float v = tr[px][cg + j];
            unsigned short h = f2bf(v);
            hv[j] = (short)h;
            lv[j] = (short)f2bf(v - bf2f(h));
        }
        int chunk = cg >> 5;
        int off   = cg & 31;
        size_t base = ((size_t)b * HW_ + hw0 + px) * 32 + off;
        *(s16x8*)(Xs + (size_t)(0 + chunk) * PSTR + base) = hv;   // hi planes 0,1
        *(s16x8*)(Xs + (size_t)(2 + chunk) * PSTR + base) = lv;   // lo planes 2,3
    }
}

// ---------------------------------------------------------------------------
// K5: split-bf16 MFMA conv (3x3, pad 1, per-sample weights).
// Grid 1024 blocks (XCD-swizzled), 256 thr (4 waves).
// Block: 2 output rows x 128 px, all 64 oc, one sample.
// Wave wv: row = wv&1, px-half = wv>>1 (4 ntiles of 16 px); acc[4 oct][4 nt].
// 4 phases: plane ph = (hi c0),(hi c1),(lo c0),(lo c1); hi: Wh*X + Wl*X, lo: Wh*X.
// LDS per phase: [4 rows][65 col-pairs][8 slots][8ch] bf16 = 33,280 B,
// slot = (u*4+q) ^ (pair&7)  (conflict-free both sides).
// T14: next phase's global loads issued to regs before tap loop; ds_write after barrier.
// ---------------------------------------------------------------------------
#define NGRAN 2080                 // 4*65*8 16B-granules per phase
__launch_bounds__(256, 2)
__global__ void conv_mfma(const unsigned short* __restrict__ Xs,  // 4-plane input
                          const unsigned short* __restrict__ Wh,
                          const unsigned short* __restrict__ Wl,
                          const float* __restrict__ bias,         // [B][64]
                          unsigned short* __restrict__ Ys,        // 4-plane output
                          float* __restrict__ Yf,                 // final fp32 NCHW
                          int final_layer) {
    const int bid  = blockIdx.x;
    const int wg   = (bid & 7) * 128 + (bid >> 3);   // XCD-bijective swizzle
    const int b    = wg >> 6;
    const int py0  = (wg & 63) * 2;

    const int t  = threadIdx.x;
    const int l  = t & 63;
    const int wv = t >> 6;
    const int lq = l >> 4;
    const int ln = l & 15;
    const int rw = wv & 1;           // output row within block
    const int hx = wv >> 1;          // px half

    __shared__ __align__(16) unsigned short lds_x[NGRAN * 8];   // 33,280 B

    f32x4 acc[4][4];
#pragma unroll
    for (int o = 0; o < 4; ++o)
#pragma unroll
        for (int n = 0; n < 4; ++n)
#pragma unroll
            for (int r = 0; r < 4; ++r) acc[o][n][r] = 0.f;

    const size_t pbase = (size_t)b * HW_ * 32;       // within-plane sample base
    const size_t wbase = (size_t)b * OC_ * 9 * 64;

    // ---- staging helpers (granule g: s_lin fastest, then pair, then row) ----
    s16x8 stg[9];
    int   stgoff[9];                                  // LDS short offsets

#define ISSUE(ph)                                                              \
    {                                                                          \
        const unsigned short* pl_ = Xs + (size_t)(ph) * PSTR + pbase;          \
        _Pragma("unroll")                                                      \
        for (int i = 0; i < 9; ++i) {                                          \
            int g = t + i * 256;                                               \
            if (i < 8 || t < (NGRAN - 2048)) {                                 \
                int s_lin = g & 7;                                             \
                int pr    = (g >> 3) % 65;                                     \
                int row   = (g >> 3) / 65;                                     \
                int u = s_lin >> 2, q = s_lin & 3;                             \
                int ic = 2 * pr + u - 1;                                       \
                int ir = py0 + row - 1;                                        \
                s16x8 v;                                                       \
                _Pragma("unroll")                                              \
                for (int j = 0; j < 8; ++j) v[j] = 0;                          \
                if ((unsigned)ir < (unsigned)H_ && (unsigned)ic < (unsigned)W_)\
                    v = *(const s16x8*)(pl_ + ((size_t)(ir * W_ + ic)) * 32 + q * 8); \
                stg[i] = v;                                                    \
                stgoff[i] = (((row * 65 + pr) << 3) + (s_lin ^ (pr & 7))) << 3;\
            }                                                                  \
        }                                                                      \
    }

#define WRITE_STG()                                                            \
    {                                                                          \
        _Pragma("unroll")                                                      \
        for (int i = 0; i < 9; ++i)                                            \
            if (i < 8 || t < (NGRAN - 2048))                                   \
                *(s16x8*)&lds_x[stgoff[i]] = stg[i];                           \
    }

    // prologue: stage phase 0
    ISSUE(0);
    WRITE_STG();
    __syncthreads();

    for (int ph = 0; ph < 4; ++ph) {
        const int hi    = (ph < 2);
        const int cbase = (ph & 1) * 32;

        if (ph < 3) ISSUE(ph + 1);

        // ---- compute phase: 9 taps, A ping-pong from global (L2) ----
        s16x8 Ah[2][4], Al[2][4];
#define LOADA(tp, pp)                                                          \
        {                                                                      \
            _Pragma("unroll")                                                  \
            for (int oct = 0; oct < 4; ++oct) {                                \
                size_t off = wbase + ((size_t)((oct * 16 + ln) * 9 + (tp))) * 64 \
                             + cbase + lq * 8;                                 \
                Ah[pp][oct] = *(const s16x8*)(Wh + off);                       \
                if (hi) Al[pp][oct] = *(const s16x8*)(Wl + off);               \
            }                                                                  \
        }
        LOADA(0, 0);
#pragma unroll
        for (int tap = 0; tap < 9; ++tap) {
            const int pp = tap & 1;
            if (tap < 8) LOADA(tap + 1, pp ^ 1);
            const int ky  = tap / 3;
            const int kx  = tap % 3;
            const int row = rw + ky;
            s16x8 Bv[4];
#pragma unroll
            for (int nt = 0; nt < 4; ++nt) {
                int col  = hx * 64 + nt * 16 + ln + kx;      // 0..129
                int pr   = col >> 1, u = col & 1;
                int slot = (u * 4 + lq) ^ (pr & 7);
                Bv[nt] = *(const s16x8*)&lds_x[(((row * 65 + pr) << 3) + slot) << 3];
            }
#pragma unroll
            for (int oct = 0; oct < 4; ++oct)
#pragma unroll
                for (int nt = 0; nt < 4; ++nt)
                    acc[oct][nt] = __builtin_amdgcn_mfma_f32_16x16x32_bf16(
                        Ah[pp][oct], Bv[nt], acc[oct][nt], 0, 0, 0);
            if (hi) {
#pragma unroll
                for (int oct = 0; oct < 4; ++oct)
#pragma unroll
                    for (int nt = 0; nt < 4; ++nt)
                        acc[oct][nt] = __builtin_amdgcn_mfma_f32_16x16x32_bf16(
                            Al[pp][oct], Bv[nt], acc[oct][nt], 0, 0, 0);
            }
        }
#undef LOADA

        __syncthreads();                 // all waves done reading this phase
        if (ph < 3) {
            WRITE_STG();                 // implicit vmcnt wait on stg values
            __syncthreads();
        }
    }

    // ---- epilogue: bias + store ----
    // C/D layout: col = ln = px-in-tile, row = lq*4 + r = oc-in-tile.
    float bia[4][4];
#pragma unroll
    for (int oct = 0; oct < 4; ++oct)
#pragma unroll
        for (int r = 0; r < 4; ++r)
            bia[oct][r] = bias[b * OC_ + oct * 16 + lq * 4 + r];

    const int orow = py0 + rw;
    if (!final_layer) {
#pragma unroll
        for (int oct = 0; oct < 4; ++oct)
#pragma unroll
            for (int nt = 0; nt < 4; ++nt) {
                int px = hx * 64 + nt * 16 + ln;
                size_t pxl = (size_t)b * HW_ + orow * W_ + px;
                int oc0   = oct * 16 + lq * 4;
                int chunk = oc0 >> 5;
                int off   = oc0 & 31;
                s16x4 hv, lv;
#pragma unroll
                for (int r = 0; r < 4; ++r) {
                    float v = acc[oct][nt][r] + bia[oct][r];
                    unsigned short h = f2bf(v);
                    hv[r] = (short)h;
                    lv[r] = (short)f2bf(v - bf2f(h));
                }
                *(s16x4*)(Ys + (size_t)(0 + chunk) * PSTR + pxl * 32 + off) = hv;
                *(s16x4*)(Ys + (size_t)(2 + chunk) * PSTR + pxl * 32 + off) = lv;
            }
    } else {
#pragma unroll
        for (int oct = 0; oct < 4; ++oct)
#pragma unroll
            for (int nt = 0; nt < 4; ++nt) {
                int px = hx * 64 + nt * 16 + ln;
#pragma unroll
                for (int r = 0; r < 4; ++r) {
                    int oc = oct * 16 + lq * 4 + r;
                    Yf[((size_t)(b * OC_ + oc)) * HW_ + orow * W_ + px] =
                        acc[oct][nt][r] + bia[oct][r];
                }
            }
    }
#undef ISSUE
#undef WRITE_STG
}

// ---------------------------------------------------------------------------
// Launch
// ---------------------------------------------------------------------------
extern "C" void kernel_launch(void* const* d_in, const int* in_sizes, int n_in,
                              void* d_out, int out_size, void* d_ws, size_t ws_size,
                              hipStream_t stream) {
    const float* x   = (const float*)d_in[0];
    const float* cw1 = (const float*)d_in[1];
    const float* cw2 = (const float*)d_in[2];
    const float* w1  = (const float*)d_in[3];
    const float* w2  = (const float*)d_in[4];
    const float* w3  = (const float*)d_in[5];
    const float* b1  = (const float*)d_in[6];
    const float* b2  = (const float*)d_in[7];
    const float* b3  = (const float*)d_in[8];

    char* ws = (char*)d_ws;
    float* pooled = (float*)(ws + 0);            //  4 KB
    float* coeff  = (float*)(ws + 4096);         // 16 KB
    float* ab_all = (float*)(ws + 20480);        // 12 KB
    const size_t WSZ = (size_t)B_ * OC_ * 9 * 64 * 2;   // 1,179,648 B per W array
    unsigned short* Wh1 = (unsigned short*)(ws + 32768);
    unsigned short* Wl1 = (unsigned short*)(ws + 32768 + 1 * WSZ);
    unsigned short* Wh2 = (unsigned short*)(ws + 32768 + 2 * WSZ);
    unsigned short* Wl2 = (unsigned short*)(ws + 32768 + 3 * WSZ);
    unsigned short* Wh3 = (unsigned short*)(ws + 32768 + 4 * WSZ);
    unsigned short* Wl3 = (unsigned short*)(ws + 32768 + 5 * WSZ);
    const size_t SOFF = 32768 + 6 * WSZ;                 // 7,110,656
    const size_t SSZ  = 4 * PSTR * 2;                    // 67,108,864 B per stage
    unsigned short* S0 = (unsigned short*)(ws + SOFF);
    unsigned short* S1 = (unsigned short*)(ws + SOFF + SSZ);
    // total = 7,110,656 + 2*67,108,864 = 141,328,384 B (same as prev round)

    float* ab1 = ab_all;
    float* ab2 = ab_all + B_ * OC_;
    float* ab3 = ab_all + 2 * B_ * OC_;

    pool_kernel<<<B_ * C_, 256, 0, stream>>>(x, pooled);
    control_kernel<<<B_, 64, 0, stream>>>(pooled, cw1, cw2, b1, b2, b3, coeff, ab_all);
    {
        dim3 g(2304, 3);
        aggw_split<<<g, 256, 0, stream>>>(coeff, w1, w2, w3,
                                          Wh1, Wl1, Wh2, Wl2, Wh3, Wl3);
    }
    {
        dim3 g(HW_ / 64, B_);
        xcvt_kernel<<<g, 256, 0, stream>>>(x, S0);
    }
    conv_mfma<<<1024, 256, 0, stream>>>(S0, Wh1, Wl1, ab1, S1, nullptr, 0);
    conv_mfma<<<1024, 256, 0, stream>>>(S1, Wh2, Wl2, ab2, S0, nullptr, 0);
    conv_mfma<<<1024, 256, 0, stream>>>(S0, Wh3, Wl3, ab3, nullptr, (float*)d_out, 1);
}